// Round 7
// baseline (2011.044 us; speedup 1.0000x reference)
//
#include <hip/hip_runtime.h>

// VQ codebook: z_e (16,256,32,32) f32, codebook (8192,256) f32.
// out f32: z_q_st[4194304] | loss[1] | codes[16384].
// n = b*1024+hw; z_flat[n][d] = z_e[b*262144 + d*1024 + hw]
// Reference: dist = fl32(zz - 2*dot), dot = sequential f32 FMA chain d=0..255,
// argmin ties -> lowest index (validated bitwise in round 2).
//
// Pipeline: bf16 hh-only MFMA screen (32x32x16, z register-stationary,
// codebook double-buffered through 128KB LDS via global_load_lds) with
// PER-BLOCK ROTATED tile sweep (decorrelates L2: all blocks reading the same
// lines in lockstep serialized at L2 banks -> 3.2TB/s aggregate in r6) and
// BLOCK-LOCAL screening threshold (no global atomics in hot loop)
// -> candidate append -> fused exact rescore + z_q/loss.

#define CAP 64
#define MRG_C 1.96e-4f   // dot-domain: 1.5*max ulp(zz) + 2*bf16 screen err bound

typedef short bf16x8 __attribute__((ext_vector_type(8)));
typedef float f32x16 __attribute__((ext_vector_type(16)));

__device__ __forceinline__ unsigned short f2bf(float f) {
    unsigned u = __float_as_uint(f);
    return (unsigned short)((u + 0x7fffu + ((u >> 16) & 1u)) >> 16);
}
__device__ __forceinline__ void gload_lds16(const void* g, void* l) {
    __builtin_amdgcn_global_load_lds(
        (const __attribute__((address_space(1))) void*)g,
        (__attribute__((address_space(3))) void*)l, 16, 0, 0);
}

// ---- ws byte layout (big path) ----
#define ZN_B      0u          // f32[16384]
#define CNT_B     65536u      // u32[16384]
#define CAND_B    131072u     // i32[16384*CAP] = 4 MB
#define ZH_B      4456448u    // bf16[16384][256] = 8 MB
#define CH_B      12845056u   // bf16[8192][256] = 4 MB
#define WS_NEED   17039360u

// ---------------- prep: z norms + bf16 transpose (fused) ----------------
__global__ __launch_bounds__(256)
void prep_z_kernel(const float* __restrict__ z, float* __restrict__ zn,
                   unsigned short* __restrict__ zh) {
    __shared__ float zs[64][257];
    const int tid = threadIdx.x;
    const int nbase = blockIdx.x * 64;
    const int b = nbase >> 10, hw0 = nbase & 1023;
    const int lane = tid & 63;
    const int w = tid >> 6;
    // stage 64 rows x 256 d, coalesced (lanes = consecutive hw)
#pragma unroll 8
    for (int it = 0; it < 64; ++it) {
        int d = it * 4 + w;
        zs[lane][d] = z[(size_t)b * 262144 + (size_t)d * 1024 + hw0 + lane];
    }
    __syncthreads();
    // sequential per-row norm (same chain as reference-validated round 2)
    if (tid < 64) {
        float s = 0.f;
        for (int d = 0; d < 256; ++d) {
            float v = zs[tid][d];
            s += v * v;
        }
        zn[nbase + tid] = s;
    }
    // bf16 write-out, coalesced ushort4
#pragma unroll 4
    for (int it = 0; it < 16; ++it) {
        int idx = it * 256 + tid;
        int row = idx >> 6;
        int d4 = idx & 63;
        ushort4 hv;
        hv.x = f2bf(zs[row][d4 * 4 + 0]);
        hv.y = f2bf(zs[row][d4 * 4 + 1]);
        hv.z = f2bf(zs[row][d4 * 4 + 2]);
        hv.w = f2bf(zs[row][d4 * 4 + 3]);
        ((ushort4*)(zh + (size_t)(nbase + row) * 256))[d4] = hv;
    }
}

// ---------------- prep: codebook -> bf16 ----------------
__global__ __launch_bounds__(256)
void split_c_kernel(const float* __restrict__ cb, unsigned short* __restrict__ ch) {
    int gid = blockIdx.x * 256 + threadIdx.x;     // float4 index; 524288 total
    float4 v = ((const float4*)cb)[gid];
    ushort4 hv;
    hv.x = f2bf(v.x); hv.y = f2bf(v.y); hv.z = f2bf(v.z); hv.w = f2bf(v.w);
    ((ushort4*)ch)[gid] = hv;
}

// ---------------- screening GEMM (32x32x16, z stationary) ----------------
// 256 blocks x 512 thr (8 waves = 2 rowgroups x 4 code-quarters).
// Block owns 64 z-rows; streams all 8192 codes in 64 tiles of 128 codes,
// sweep ROTATED per block (toff) so co-XCD CUs touch different L2 lines.
__global__ __launch_bounds__(512)
void gemm_screen32(const unsigned short* __restrict__ zh,
                   const unsigned short* __restrict__ ch,
                   unsigned* __restrict__ cnt, int* __restrict__ cand) {
    __shared__ char smem[131072];   // 2 x (128 codes x 512B), granule-swizzled
    const int tid = threadIdx.x;
    const int l = tid & 63;
    const int wv = tid >> 6;
    const int rg = wv >> 2;       // row-group (0..1)
    const int cq = wv & 3;        // code-quarter (0..3)
    const int l5 = l >> 5, l31 = l & 31;
    const int n0 = blockIdx.x * 64;
    const int toff = (blockIdx.x * 37) & 63;   // odd stride: spreads any mapping

    // A fragments: 32 z-rows x all 256 d in registers.
    // 32x32x16 A-frag: lane holds A[row=l&31][k = 8*(l>>5) + j]  (HW-verified)
    bf16x8 a[16];
    {
        const unsigned short* zrow = zh + (size_t)(n0 + rg * 32 + l31) * 256;
#pragma unroll
        for (int k = 0; k < 16; ++k)
            a[k] = *(const bf16x8*)(zrow + k * 16 + l5 * 8);
    }

    // per-lane staging source offsets (shorts), tile-invariant. LDS dest is
    // linear (base+lane*16); XOR granule swizzle applied to SOURCE address:
    // phys granule p holds source granule p ^ (code&31).
    int soff[8];
#pragma unroll
    for (int j = 0; j < 8; ++j) {
        int cl = wv * 16 + j * 2 + l5;
        soff[j] = cl * 256 + ((l31 ^ (cl & 31)) * 8);
    }

    // block-LOCAL running max per output row (this wave's code-quarter slice);
    // tau is a stale-low-safe lower bound of (row slice max - margin).
    float best[16], tau[16];
#pragma unroll
    for (int r = 0; r < 16; ++r) { best[r] = -3.0e38f; tau[r] = 3.0e38f; }

    // prologue: stage tile toff into buffer 0
    {
        const unsigned short* src = ch + (size_t)toff * 32768;
#pragma unroll
        for (int j = 0; j < 8; ++j)
            gload_lds16(src + soff[j], smem + wv * 8192 + j * 1024);
    }

    for (int t = 0; t < 64; ++t) {
        // drains this tile's loads; confirms all waves done reading other buf
        __syncthreads();
        const char* cur = smem + (t & 1) * 65536;
        if (t < 63) {   // issue next tile's loads; land during compute
            const int tt1 = (t + 1 + toff) & 63;
            const unsigned short* src = ch + (size_t)tt1 * 32768;
            char* nxt = smem + ((t + 1) & 1) * 65536 + wv * 8192;
#pragma unroll
            for (int j = 0; j < 8; ++j)
                gload_lds16(src + soff[j], nxt + j * 1024);
        }
        // compute: 16 chained MFMAs
        f32x16 acc;
#pragma unroll
        for (int r = 0; r < 16; ++r) acc[r] = 0.f;
        const int lrbase = (cq * 32 + l31) * 512;
#pragma unroll
        for (int k = 0; k < 16; ++k) {
            bf16x8 b = *(const bf16x8*)(cur + lrbase + (((2 * k + l5) ^ l31) << 4));
            acc = __builtin_amdgcn_mfma_f32_32x32x16_bf16(a[k], b, acc, 0, 0, 0);
        }
#pragma unroll
        for (int r = 0; r < 16; ++r) best[r] = fmaxf(best[r], acc[r]);
        // refresh tau every 4 tiles: pure-local shfl reduce, NO memory ops
        if ((t == 0) || ((t & 3) == 3)) {
#pragma unroll
            for (int r = 0; r < 16; ++r) {
                float m = best[r];
#pragma unroll
                for (int msk = 1; msk <= 16; msk <<= 1)
                    m = fmaxf(m, __shfl_xor(m, msk));
                tau[r] = m - MRG_C;
            }
        }
        // candidate appends (rare)
        {
            const int code = ((t + toff) & 63) * 128 + cq * 32 + l31;
#pragma unroll
            for (int r = 0; r < 16; ++r) {
                if (acc[r] >= tau[r]) {
                    int n = n0 + rg * 32 + 4 * l5 + (r & 3) + 8 * (r >> 2);
                    unsigned slot = atomicAdd(&cnt[n], 1u);
                    if (slot < CAP) cand[n * CAP + slot] = code;
                }
            }
        }
    }
}

// ---------------- fused exact rescore + z_q gather + loss ----------------
__global__ __launch_bounds__(256)
void select_finalize(const float* __restrict__ z, const float* __restrict__ cb,
                     const float* __restrict__ zn, const unsigned* __restrict__ cnt,
                     const int* __restrict__ cand,
                     float* __restrict__ out) {
    __shared__ float zs[64][257];
    __shared__ int codes_s[64];
    __shared__ float wsum[4];
    const int tid = threadIdx.x;
    const int nbase = blockIdx.x * 64;
    const int b = nbase >> 10, hw0 = nbase & 1023;
    const int lane = tid & 63;
    const int w = tid >> 6;

#pragma unroll 8
    for (int it = 0; it < 64; ++it) {
        int d = it * 4 + w;
        zs[lane][d] = z[(size_t)b * 262144 + (size_t)d * 1024 + hw0 + lane];
    }
    __syncthreads();

#pragma unroll 1
    for (int rr = 0; rr < 16; ++rr) {
        const int ridx = w * 16 + rr;
        const int n = nbase + ridx;
        const unsigned c = cnt[n];
        const float zz = zn[n];
        float bs; int bi;
        if (c > 0 && c <= CAP) {
            float ss = 3.0e38f; int myk = 0x7fffffff;
            if (lane < (int)c) {
                myk = cand[n * CAP + lane];
                const float* cr = cb + (size_t)myk * 256;
                float dot = 0.f;
#pragma unroll 8
                for (int d4 = 0; d4 < 64; ++d4) {   // exact sequential chain
                    float4 cv = ((const float4*)cr)[d4];
                    dot = fmaf(zs[ridx][d4 * 4 + 0], cv.x, dot);
                    dot = fmaf(zs[ridx][d4 * 4 + 1], cv.y, dot);
                    dot = fmaf(zs[ridx][d4 * 4 + 2], cv.z, dot);
                    dot = fmaf(zs[ridx][d4 * 4 + 3], cv.w, dot);
                }
                ss = zz - 2.0f * dot;   // reproduces reference score rounding
            }
            bs = ss; bi = myk;
        } else {
            // overflow/empty fallback: exact full scan
            bs = 3.0e38f; bi = 0x7fffffff;
            for (int base = 0; base < 8192; base += 64) {
                const float* cr = cb + (size_t)(base + lane) * 256;
                float dot = 0.f;
#pragma unroll 8
                for (int d4 = 0; d4 < 64; ++d4) {
                    float4 cv = ((const float4*)cr)[d4];
                    dot = fmaf(zs[ridx][d4 * 4 + 0], cv.x, dot);
                    dot = fmaf(zs[ridx][d4 * 4 + 1], cv.y, dot);
                    dot = fmaf(zs[ridx][d4 * 4 + 2], cv.z, dot);
                    dot = fmaf(zs[ridx][d4 * 4 + 3], cv.w, dot);
                }
                float sc = zz - 2.0f * dot;
                int k = base + lane;
                if (sc < bs || (sc == bs && k < bi)) { bs = sc; bi = k; }
            }
        }
#pragma unroll
        for (int m = 1; m <= 32; m <<= 1) {
            float ps = __shfl_xor(bs, m);
            int pi = __shfl_xor(bi, m);
            if (ps < bs || (ps == bs && pi < bi)) { bs = ps; bi = pi; }
        }
        if (lane == 0) { codes_s[ridx] = bi; out[4194305 + n] = (float)bi; }
    }
    __syncthreads();

    const int code = codes_s[lane];
    const float* crow = cb + (size_t)code * 256;
    float part = 0.f;
#pragma unroll 8
    for (int j = 0; j < 64; ++j) {
        int d = w * 64 + j;
        float cv = crow[d];
        float ze = zs[lane][d];
        out[(size_t)b * 262144 + (size_t)d * 1024 + hw0 + lane] = cv;
        float diff = ze - cv;
        part += diff * diff;
    }
#pragma unroll
    for (int off = 32; off > 0; off >>= 1) part += __shfl_down(part, off);
    if (lane == 0) wsum[w] = part;
    __syncthreads();
    if (tid == 0) {
        float t = (wsum[0] + wsum[1] + wsum[2] + wsum[3]) * (1.25f / 4194304.f);
        atomicAdd(out + 4194304, t);
    }
}

// ================= fallback path (round-2 kernels, ws-small case) =================
#define NT 128
#define KT 128
#define DC 64
#define KS 4
#define KRANGE (8192 / KS)
#define PSCORE_OFF 32768
#define PIDX_OFF (32768 + KS * 16384)

__global__ __launch_bounds__(256)
void znorm_kernel(const float* __restrict__ z, float* __restrict__ zn) {
    int n = blockIdx.x * 256 + threadIdx.x;
    int b = n >> 10, hw = n & 1023;
    const float* zp = z + (size_t)b * 262144 + hw;
    float s = 0.f;
    for (int d = 0; d < 256; ++d) {
        float v = zp[(size_t)d << 10];
        s += v * v;
    }
    zn[n] = s;
}

__global__ __launch_bounds__(256, 2)
void dist_argmin_kernel(const float* __restrict__ z, const float* __restrict__ cb,
                        const float* __restrict__ zn,
                        float* __restrict__ pscore, int* __restrict__ pidx) {
    __shared__ float zs[DC][NT];
    __shared__ float cs[DC][KT];
    const int tid = threadIdx.x;
    const int tn = tid & 15;
    const int tk = tid >> 4;
    const int n0 = blockIdx.x * NT;
    const int b = n0 >> 10;
    const int hw0 = n0 & 1023;
    const float* zb = z + (size_t)b * 262144 + hw0;
    const int k0base = blockIdx.y * KRANGE;
    float zzr[8];
#pragma unroll
    for (int i = 0; i < 8; ++i) {
        int row = (i < 4) ? (tn * 4 + i) : (64 + tn * 4 + (i - 4));
        zzr[i] = zn[n0 + row];
    }
    float best[8]; int bidx[8];
#pragma unroll
    for (int i = 0; i < 8; ++i) { best[i] = 3.0e38f; bidx[i] = 0; }
    for (int kt = 0; kt < KRANGE / KT; ++kt) {
        const int k0 = k0base + kt * KT;
        float acc[8][8];
#pragma unroll
        for (int i = 0; i < 8; ++i)
#pragma unroll
            for (int j = 0; j < 8; ++j) acc[i][j] = 0.f;
        for (int dc = 0; dc < 256; dc += DC) {
            __syncthreads();
#pragma unroll
            for (int it = 0; it < 8; ++it) {
                int idx = it * 256 + tid;
                int d = idx >> 5, nv = idx & 31;
                float4 v = *(const float4*)(zb + (size_t)(dc + d) * 1024 + nv * 4);
                *(float4*)&zs[d][nv * 4] = v;
            }
#pragma unroll
            for (int it = 0; it < 8; ++it) {
                int idx = it * 256 + tid;
                int k = idx >> 4, dv = idx & 15;
                float4 v = *(const float4*)(cb + (size_t)(k0 + k) * 256 + dc + dv * 4);
                int colv = k ^ ((dv & 7) << 2);
                cs[dv * 4 + 0][colv] = v.x;
                cs[dv * 4 + 1][colv] = v.y;
                cs[dv * 4 + 2][colv] = v.z;
                cs[dv * 4 + 3][colv] = v.w;
            }
            __syncthreads();
#pragma unroll 2
            for (int d = 0; d < DC; ++d) {
                int swz = ((d >> 2) & 7) << 2;
                float4 a0 = *(const float4*)&zs[d][tn * 4];
                float4 a1 = *(const float4*)&zs[d][64 + tn * 4];
                float4 b0 = *(const float4*)&cs[d][(tk * 4) ^ swz];
                float4 b1 = *(const float4*)&cs[d][(64 + tk * 4) ^ swz];
                float av[8] = {a0.x, a0.y, a0.z, a0.w, a1.x, a1.y, a1.z, a1.w};
                float bv[8] = {b0.x, b0.y, b0.z, b0.w, b1.x, b1.y, b1.z, b1.w};
#pragma unroll
                for (int i = 0; i < 8; ++i)
#pragma unroll
                    for (int j = 0; j < 8; ++j)
                        acc[i][j] = fmaf(av[i], bv[j], acc[i][j]);
            }
        }
#pragma unroll
        for (int j = 0; j < 8; ++j) {
            int kloc = (j < 4) ? (tk * 4 + j) : (64 + tk * 4 + (j - 4));
            int kk = k0 + kloc;
#pragma unroll
            for (int i = 0; i < 8; ++i) {
                float s = zzr[i] - 2.0f * acc[i][j];
                if (s < best[i]) { best[i] = s; bidx[i] = kk; }
            }
        }
    }
    __syncthreads();
    float* sredf = &zs[0][0];
    int* sredi = (int*)&cs[0][0];
#pragma unroll
    for (int i = 0; i < 8; ++i) {
        int row = (i < 4) ? (tn * 4 + i) : (64 + tn * 4 + (i - 4));
        sredf[row * 16 + tk] = best[i];
        sredi[row * 16 + tk] = bidx[i];
    }
    __syncthreads();
    if (tid < NT) {
        float bs = sredf[tid * 16];
        int bi = sredi[tid * 16];
#pragma unroll
        for (int t = 1; t < 16; ++t) {
            float s = sredf[tid * 16 + t];
            int ix = sredi[tid * 16 + t];
            if (s < bs || (s == bs && ix < bi)) { bs = s; bi = ix; }
        }
        pscore[blockIdx.y * 16384 + n0 + tid] = bs;
        pidx[blockIdx.y * 16384 + n0 + tid] = bi;
    }
}

__global__ __launch_bounds__(256)
void finalize_kernel(const float* __restrict__ z, const float* __restrict__ cb,
                     const float* __restrict__ pscore, const int* __restrict__ pidx,
                     float* __restrict__ out) {
    __shared__ int codes_s[64];
    __shared__ float wsum[4];
    const int nbase = blockIdx.x * 64;
    const int tid = threadIdx.x;
    if (tid < 64) {
        int n = nbase + tid;
        float bs = pscore[n];
        int bi = pidx[n];
#pragma unroll
        for (int p = 1; p < KS; ++p) {
            float s = pscore[p * 16384 + n];
            int ix = pidx[p * 16384 + n];
            if (s < bs || (s == bs && ix < bi)) { bs = s; bi = ix; }
        }
        codes_s[tid] = bi;
        out[4194305 + n] = (float)bi;
    }
    __syncthreads();
    const int lane = tid & 63;
    const int w = tid >> 6;
    const int n = nbase + lane;
    const int b = n >> 10, hw = n & 1023;
    const int code = codes_s[lane];
    const float* crow = cb + (size_t)code * 256;
    const float* zrow = z + (size_t)b * 262144 + hw;
    float* orow = out + (size_t)b * 262144 + hw;
    float part = 0.f;
    for (int j = 0; j < 64; ++j) {
        int d = w * 64 + j;
        float cv = crow[d];
        float ze = zrow[(size_t)d * 1024];
        orow[(size_t)d * 1024] = cv;
        float diff = ze - cv;
        part += diff * diff;
    }
#pragma unroll
    for (int off = 32; off > 0; off >>= 1) part += __shfl_down(part, off);
    if (lane == 0) wsum[w] = part;
    __syncthreads();
    if (tid == 0) {
        float t = (wsum[0] + wsum[1] + wsum[2] + wsum[3]) * (1.25f / 4194304.f);
        atomicAdd(out + 4194304, t);
    }
}

// ================= launcher =================
extern "C" void kernel_launch(void* const* d_in, const int* in_sizes, int n_in,
                              void* d_out, int out_size, void* d_ws, size_t ws_size,
                              hipStream_t stream) {
    const float* z = (const float*)d_in[0];
    const float* cb = (const float*)d_in[1];
    float* out = (float*)d_out;
    char* wsb = (char*)d_ws;

    if (ws_size >= WS_NEED) {
        float* zn = (float*)(wsb + ZN_B);
        unsigned* cnt = (unsigned*)(wsb + CNT_B);
        int* cand = (int*)(wsb + CAND_B);
        unsigned short* zh = (unsigned short*)(wsb + ZH_B);
        unsigned short* ch = (unsigned short*)(wsb + CH_B);

        hipMemsetAsync(wsb + CNT_B, 0, 65536, stream);
        hipMemsetAsync(out + 4194304, 0, sizeof(float), stream);

        prep_z_kernel<<<256, 256, 0, stream>>>(z, zn, zh);
        split_c_kernel<<<2048, 256, 0, stream>>>(cb, ch);
        gemm_screen32<<<256, 512, 0, stream>>>(zh, ch, cnt, cand);
        select_finalize<<<256, 256, 0, stream>>>(z, cb, zn, cnt, cand, out);
    } else {
        float* zn = (float*)wsb;
        float* pscore = (float*)wsb + PSCORE_OFF;
        int* pidx = (int*)((float*)wsb + PIDX_OFF);
        znorm_kernel<<<64, 256, 0, stream>>>(z, zn);
        dim3 grid(16384 / NT, KS);
        dist_argmin_kernel<<<grid, 256, 0, stream>>>(z, cb, zn, pscore, pidx);
        hipMemsetAsync(out + 4194304, 0, sizeof(float), stream);
        finalize_kernel<<<16384 / 64, 256, 0, stream>>>(z, cb, pscore, pidx, out);
    }
}

// Round 8
// 481.559 us; speedup vs baseline: 4.1761x; 4.1761x over previous
//
#include <hip/hip_runtime.h>

// VQ codebook: z_e (16,256,32,32) f32, codebook (8192,256) f32.
// out f32: z_q_st[4194304] | loss[1] | codes[16384].
// n = b*1024+hw; z_flat[n][d] = z_e[b*262144 + d*1024 + hw]
// Reference: dist = fl32(zz - 2*dot), dot = sequential f32 FMA chain d=0..255,
// argmin ties -> lowest index (validated bitwise in round 2).
//
// Pipeline: bf16 hh-only MFMA screen (32x32x16, z register-stationary,
// codebook double-buffered through 128KB LDS via global_load_lds).
// Threshold = per-row block max combined across ALL 4 code-quarter waves via
// LDS ds_atomicMax rowmax[64], refreshed every tile (r7 bug: per-wave-slice
// tau was 4x too loose -> CAP overflow -> 1.7ms exact fallback).
// Sweep offset decorrelated only WITHIN an XCD (toff=((bid>>3)&31)*2):
// ~2MB L2-resident working set, no same-line concurrency inside an L2.

#define CAP 64
#define MRG_C 1.96e-4f   // dot-domain: 1.5*max ulp(zz) + 2*bf16 screen err bound

typedef short bf16x8 __attribute__((ext_vector_type(8)));
typedef float f32x16 __attribute__((ext_vector_type(16)));

__device__ __forceinline__ unsigned short f2bf(float f) {
    unsigned u = __float_as_uint(f);
    return (unsigned short)((u + 0x7fffu + ((u >> 16) & 1u)) >> 16);
}
// monotone float<->uint key (total order matches float order)
__device__ __forceinline__ unsigned fkey(float f) {
    unsigned u = __float_as_uint(f);
    return (u & 0x80000000u) ? ~u : (u | 0x80000000u);
}
__device__ __forceinline__ float funkey(unsigned k) {
    unsigned u = (k & 0x80000000u) ? (k ^ 0x80000000u) : ~k;
    return __uint_as_float(u);
}
__device__ __forceinline__ void gload_lds16(const void* g, void* l) {
    __builtin_amdgcn_global_load_lds(
        (const __attribute__((address_space(1))) void*)g,
        (__attribute__((address_space(3))) void*)l, 16, 0, 0);
}

// ---- ws byte layout (big path) ----
#define ZN_B      0u          // f32[16384]
#define CNT_B     65536u      // u32[16384]
#define CAND_B    131072u     // i32[16384*CAP] = 4 MB
#define ZH_B      4456448u    // bf16[16384][256] = 8 MB
#define CH_B      12845056u   // bf16[8192][256] = 4 MB
#define WS_NEED   17039360u

// ---------------- prep: z norms + bf16 transpose (fused) ----------------
__global__ __launch_bounds__(256)
void prep_z_kernel(const float* __restrict__ z, float* __restrict__ zn,
                   unsigned short* __restrict__ zh) {
    __shared__ float zs[64][257];
    const int tid = threadIdx.x;
    const int nbase = blockIdx.x * 64;
    const int b = nbase >> 10, hw0 = nbase & 1023;
    const int lane = tid & 63;
    const int w = tid >> 6;
#pragma unroll 8
    for (int it = 0; it < 64; ++it) {
        int d = it * 4 + w;
        zs[lane][d] = z[(size_t)b * 262144 + (size_t)d * 1024 + hw0 + lane];
    }
    __syncthreads();
    if (tid < 64) {
        float s = 0.f;
        for (int d = 0; d < 256; ++d) {
            float v = zs[tid][d];
            s += v * v;
        }
        zn[nbase + tid] = s;
    }
#pragma unroll 4
    for (int it = 0; it < 16; ++it) {
        int idx = it * 256 + tid;
        int row = idx >> 6;
        int d4 = idx & 63;
        ushort4 hv;
        hv.x = f2bf(zs[row][d4 * 4 + 0]);
        hv.y = f2bf(zs[row][d4 * 4 + 1]);
        hv.z = f2bf(zs[row][d4 * 4 + 2]);
        hv.w = f2bf(zs[row][d4 * 4 + 3]);
        ((ushort4*)(zh + (size_t)(nbase + row) * 256))[d4] = hv;
    }
}

// ---------------- prep: codebook -> bf16 ----------------
__global__ __launch_bounds__(256)
void split_c_kernel(const float* __restrict__ cb, unsigned short* __restrict__ ch) {
    int gid = blockIdx.x * 256 + threadIdx.x;     // float4 index; 524288 total
    float4 v = ((const float4*)cb)[gid];
    ushort4 hv;
    hv.x = f2bf(v.x); hv.y = f2bf(v.y); hv.z = f2bf(v.z); hv.w = f2bf(v.w);
    ((ushort4*)ch)[gid] = hv;
}

// ---------------- screening GEMM (32x32x16, z stationary) ----------------
// 256 blocks x 512 thr (8 waves = 2 rowgroups x 4 code-quarters).
// Block owns 64 z-rows; streams all 8192 codes in 64 tiles of 128 codes.
__global__ __launch_bounds__(512)
void gemm_screen32(const unsigned short* __restrict__ zh,
                   const unsigned short* __restrict__ ch,
                   unsigned* __restrict__ cnt, int* __restrict__ cand) {
    __shared__ char smem[131072];     // 2 x (128 codes x 512B), granule-swizzled
    __shared__ unsigned rowmax[64];   // fkey of per-row block max (all waves)
    const int tid = threadIdx.x;
    const int l = tid & 63;
    const int wv = tid >> 6;
    const int rg = wv >> 2;       // row-group (0..1)
    const int cq = wv & 3;        // code-quarter (0..3)
    const int l5 = l >> 5, l31 = l & 31;
    const int n0 = blockIdx.x * 64;
    // decorrelate sweep within an XCD only (bid%8 ~ XCD round-robin)
    const int toff = ((blockIdx.x >> 3) & 31) * 2;

    if (tid < 64) rowmax[tid] = 0u;   // 0 < fkey(x) for all finite x

    // A fragments: 32 z-rows x all 256 d in registers.
    // 32x32x16 A-frag: lane holds A[row=l&31][k = 8*(l>>5) + j]  (HW-verified)
    bf16x8 a[16];
    {
        const unsigned short* zrow = zh + (size_t)(n0 + rg * 32 + l31) * 256;
#pragma unroll
        for (int k = 0; k < 16; ++k)
            a[k] = *(const bf16x8*)(zrow + k * 16 + l5 * 8);
    }

    // per-lane staging source offsets (shorts), tile-invariant; XOR granule
    // swizzle applied to SOURCE (LDS dest is linear base+lane*16).
    int soff[8];
#pragma unroll
    for (int j = 0; j < 8; ++j) {
        int cl = wv * 16 + j * 2 + l5;
        soff[j] = cl * 256 + ((l31 ^ (cl & 31)) * 8);
    }

    const int lrbase = (cq * 32 + l31) * 512;

    // prologue: stage tile toff into buffer 0
    {
        const unsigned short* src = ch + (size_t)toff * 32768;
#pragma unroll
        for (int j = 0; j < 8; ++j)
            gload_lds16(src + soff[j], smem + wv * 8192 + j * 1024);
    }
    __syncthreads();   // loads drained; rowmax init visible
    // pre-seed rowmax with full tile-toff maxes (no appends for this pass)
    {
        f32x16 acc;
#pragma unroll
        for (int r = 0; r < 16; ++r) acc[r] = 0.f;
#pragma unroll
        for (int k = 0; k < 16; ++k) {
            bf16x8 b = *(const bf16x8*)(smem + lrbase + (((2 * k + l5) ^ l31) << 4));
            acc = __builtin_amdgcn_mfma_f32_32x32x16_bf16(a[k], b, acc, 0, 0, 0);
        }
#pragma unroll
        for (int r = 0; r < 16; ++r) {
            float m = acc[r];
#pragma unroll
            for (int msk = 1; msk <= 16; msk <<= 1)
                m = fmaxf(m, __shfl_xor(m, msk));
            if (l31 == 0)
                atomicMax(&rowmax[rg * 32 + 4 * l5 + (r & 3) + 8 * (r >> 2)], fkey(m));
        }
    }

    for (int t = 0; t < 64; ++t) {
        // drains tile-t loads (t=0: none in flight); rowmax atomics visible;
        // all waves done reading the buffer about to be restaged.
        __syncthreads();
        const char* cur = smem + (t & 1) * 65536;
        if (t < 63) {   // issue next tile's loads; land during compute
            const int tt1 = (t + 1 + toff) & 63;
            const unsigned short* src = ch + (size_t)tt1 * 32768;
            char* nxt = smem + ((t + 1) & 1) * 65536 + wv * 8192;
#pragma unroll
            for (int j = 0; j < 8; ++j)
                gload_lds16(src + soff[j], nxt + j * 1024);
        }
        // compute: 16 chained MFMAs
        f32x16 acc;
#pragma unroll
        for (int r = 0; r < 16; ++r) acc[r] = 0.f;
#pragma unroll
        for (int k = 0; k < 16; ++k) {
            bf16x8 b = *(const bf16x8*)(cur + lrbase + (((2 * k + l5) ^ l31) << 4));
            acc = __builtin_amdgcn_mfma_f32_32x32x16_bf16(a[k], b, acc, 0, 0, 0);
        }
        // slice max -> LDS rowmax (combines all 4 code-quarter waves)
#pragma unroll
        for (int r = 0; r < 16; ++r) {
            float m = acc[r];
#pragma unroll
            for (int msk = 1; msk <= 16; msk <<= 1)
                m = fmaxf(m, __shfl_xor(m, msk));
            if (l31 == 0)
                atomicMax(&rowmax[rg * 32 + 4 * l5 + (r & 3) + 8 * (r >> 2)], fkey(m));
        }
        // appends vs fresh tau (>= includes own tile; monotone -> always safe)
        {
            const int code = ((t + toff) & 63) * 128 + cq * 32 + l31;
#pragma unroll
            for (int r = 0; r < 16; ++r) {
                int row = rg * 32 + 4 * l5 + (r & 3) + 8 * (r >> 2);
                float tau = funkey(rowmax[row]) - MRG_C;
                if (acc[r] >= tau) {
                    unsigned slot = atomicAdd(&cnt[n0 + row], 1u);
                    if (slot < CAP) cand[(n0 + row) * CAP + slot] = code;
                }
            }
        }
    }
}

// ---------------- fused exact rescore + z_q gather + loss ----------------
__global__ __launch_bounds__(256)
void select_finalize(const float* __restrict__ z, const float* __restrict__ cb,
                     const float* __restrict__ zn, const unsigned* __restrict__ cnt,
                     const int* __restrict__ cand,
                     float* __restrict__ out) {
    __shared__ float zs[64][257];
    __shared__ int codes_s[64];
    __shared__ float wsum[4];
    const int tid = threadIdx.x;
    const int nbase = blockIdx.x * 64;
    const int b = nbase >> 10, hw0 = nbase & 1023;
    const int lane = tid & 63;
    const int w = tid >> 6;

#pragma unroll 8
    for (int it = 0; it < 64; ++it) {
        int d = it * 4 + w;
        zs[lane][d] = z[(size_t)b * 262144 + (size_t)d * 1024 + hw0 + lane];
    }
    __syncthreads();

#pragma unroll 1
    for (int rr = 0; rr < 16; ++rr) {
        const int ridx = w * 16 + rr;
        const int n = nbase + ridx;
        const unsigned c = cnt[n];
        const float zz = zn[n];
        float bs; int bi;
        if (c > 0 && c <= CAP) {
            float ss = 3.0e38f; int myk = 0x7fffffff;
            if (lane < (int)c) {
                myk = cand[n * CAP + lane];
                const float* cr = cb + (size_t)myk * 256;
                float dot = 0.f;
#pragma unroll 8
                for (int d4 = 0; d4 < 64; ++d4) {   // exact sequential chain
                    float4 cv = ((const float4*)cr)[d4];
                    dot = fmaf(zs[ridx][d4 * 4 + 0], cv.x, dot);
                    dot = fmaf(zs[ridx][d4 * 4 + 1], cv.y, dot);
                    dot = fmaf(zs[ridx][d4 * 4 + 2], cv.z, dot);
                    dot = fmaf(zs[ridx][d4 * 4 + 3], cv.w, dot);
                }
                ss = zz - 2.0f * dot;   // reproduces reference score rounding
            }
            bs = ss; bi = myk;
        } else {
            // overflow/empty fallback: exact full scan
            bs = 3.0e38f; bi = 0x7fffffff;
            for (int base = 0; base < 8192; base += 64) {
                const float* cr = cb + (size_t)(base + lane) * 256;
                float dot = 0.f;
#pragma unroll 8
                for (int d4 = 0; d4 < 64; ++d4) {
                    float4 cv = ((const float4*)cr)[d4];
                    dot = fmaf(zs[ridx][d4 * 4 + 0], cv.x, dot);
                    dot = fmaf(zs[ridx][d4 * 4 + 1], cv.y, dot);
                    dot = fmaf(zs[ridx][d4 * 4 + 2], cv.z, dot);
                    dot = fmaf(zs[ridx][d4 * 4 + 3], cv.w, dot);
                }
                float sc = zz - 2.0f * dot;
                int k = base + lane;
                if (sc < bs || (sc == bs && k < bi)) { bs = sc; bi = k; }
            }
        }
#pragma unroll
        for (int m = 1; m <= 32; m <<= 1) {
            float ps = __shfl_xor(bs, m);
            int pi = __shfl_xor(bi, m);
            if (ps < bs || (ps == bs && pi < bi)) { bs = ps; bi = pi; }
        }
        if (lane == 0) { codes_s[ridx] = bi; out[4194305 + n] = (float)bi; }
    }
    __syncthreads();

    const int code = codes_s[lane];
    const float* crow = cb + (size_t)code * 256;
    float part = 0.f;
#pragma unroll 8
    for (int j = 0; j < 64; ++j) {
        int d = w * 64 + j;
        float cv = crow[d];
        float ze = zs[lane][d];
        out[(size_t)b * 262144 + (size_t)d * 1024 + hw0 + lane] = cv;
        float diff = ze - cv;
        part += diff * diff;
    }
#pragma unroll
    for (int off = 32; off > 0; off >>= 1) part += __shfl_down(part, off);
    if (lane == 0) wsum[w] = part;
    __syncthreads();
    if (tid == 0) {
        float t = (wsum[0] + wsum[1] + wsum[2] + wsum[3]) * (1.25f / 4194304.f);
        atomicAdd(out + 4194304, t);
    }
}

// ================= fallback path (round-2 kernels, ws-small case) =================
#define NT 128
#define KT 128
#define DC 64
#define KS 4
#define KRANGE (8192 / KS)
#define PSCORE_OFF 32768
#define PIDX_OFF (32768 + KS * 16384)

__global__ __launch_bounds__(256)
void znorm_kernel(const float* __restrict__ z, float* __restrict__ zn) {
    int n = blockIdx.x * 256 + threadIdx.x;
    int b = n >> 10, hw = n & 1023;
    const float* zp = z + (size_t)b * 262144 + hw;
    float s = 0.f;
    for (int d = 0; d < 256; ++d) {
        float v = zp[(size_t)d << 10];
        s += v * v;
    }
    zn[n] = s;
}

__global__ __launch_bounds__(256, 2)
void dist_argmin_kernel(const float* __restrict__ z, const float* __restrict__ cb,
                        const float* __restrict__ zn,
                        float* __restrict__ pscore, int* __restrict__ pidx) {
    __shared__ float zs[DC][NT];
    __shared__ float cs[DC][KT];
    const int tid = threadIdx.x;
    const int tn = tid & 15;
    const int tk = tid >> 4;
    const int n0 = blockIdx.x * NT;
    const int b = n0 >> 10;
    const int hw0 = n0 & 1023;
    const float* zb = z + (size_t)b * 262144 + hw0;
    const int k0base = blockIdx.y * KRANGE;
    float zzr[8];
#pragma unroll
    for (int i = 0; i < 8; ++i) {
        int row = (i < 4) ? (tn * 4 + i) : (64 + tn * 4 + (i - 4));
        zzr[i] = zn[n0 + row];
    }
    float best[8]; int bidx[8];
#pragma unroll
    for (int i = 0; i < 8; ++i) { best[i] = 3.0e38f; bidx[i] = 0; }
    for (int kt = 0; kt < KRANGE / KT; ++kt) {
        const int k0 = k0base + kt * KT;
        float acc[8][8];
#pragma unroll
        for (int i = 0; i < 8; ++i)
#pragma unroll
            for (int j = 0; j < 8; ++j) acc[i][j] = 0.f;
        for (int dc = 0; dc < 256; dc += DC) {
            __syncthreads();
#pragma unroll
            for (int it = 0; it < 8; ++it) {
                int idx = it * 256 + tid;
                int d = idx >> 5, nv = idx & 31;
                float4 v = *(const float4*)(zb + (size_t)(dc + d) * 1024 + nv * 4);
                *(float4*)&zs[d][nv * 4] = v;
            }
#pragma unroll
            for (int it = 0; it < 8; ++it) {
                int idx = it * 256 + tid;
                int k = idx >> 4, dv = idx & 15;
                float4 v = *(const float4*)(cb + (size_t)(k0 + k) * 256 + dc + dv * 4);
                int colv = k ^ ((dv & 7) << 2);
                cs[dv * 4 + 0][colv] = v.x;
                cs[dv * 4 + 1][colv] = v.y;
                cs[dv * 4 + 2][colv] = v.z;
                cs[dv * 4 + 3][colv] = v.w;
            }
            __syncthreads();
#pragma unroll 2
            for (int d = 0; d < DC; ++d) {
                int swz = ((d >> 2) & 7) << 2;
                float4 a0 = *(const float4*)&zs[d][tn * 4];
                float4 a1 = *(const float4*)&zs[d][64 + tn * 4];
                float4 b0 = *(const float4*)&cs[d][(tk * 4) ^ swz];
                float4 b1 = *(const float4*)&cs[d][(64 + tk * 4) ^ swz];
                float av[8] = {a0.x, a0.y, a0.z, a0.w, a1.x, a1.y, a1.z, a1.w};
                float bv[8] = {b0.x, b0.y, b0.z, b0.w, b1.x, b1.y, b1.z, b1.w};
#pragma unroll
                for (int i = 0; i < 8; ++i)
#pragma unroll
                    for (int j = 0; j < 8; ++j)
                        acc[i][j] = fmaf(av[i], bv[j], acc[i][j]);
            }
        }
#pragma unroll
        for (int j = 0; j < 8; ++j) {
            int kloc = (j < 4) ? (tk * 4 + j) : (64 + tk * 4 + (j - 4));
            int kk = k0 + kloc;
#pragma unroll
            for (int i = 0; i < 8; ++i) {
                float s = zzr[i] - 2.0f * acc[i][j];
                if (s < best[i]) { best[i] = s; bidx[i] = kk; }
            }
        }
    }
    __syncthreads();
    float* sredf = &zs[0][0];
    int* sredi = (int*)&cs[0][0];
#pragma unroll
    for (int i = 0; i < 8; ++i) {
        int row = (i < 4) ? (tn * 4 + i) : (64 + tn * 4 + (i - 4));
        sredf[row * 16 + tk] = best[i];
        sredi[row * 16 + tk] = bidx[i];
    }
    __syncthreads();
    if (tid < NT) {
        float bs = sredf[tid * 16];
        int bi = sredi[tid * 16];
#pragma unroll
        for (int t = 1; t < 16; ++t) {
            float s = sredf[tid * 16 + t];
            int ix = sredi[tid * 16 + t];
            if (s < bs || (s == bs && ix < bi)) { bs = s; bi = ix; }
        }
        pscore[blockIdx.y * 16384 + n0 + tid] = bs;
        pidx[blockIdx.y * 16384 + n0 + tid] = bi;
    }
}

__global__ __launch_bounds__(256)
void finalize_kernel(const float* __restrict__ z, const float* __restrict__ cb,
                     const float* __restrict__ pscore, const int* __restrict__ pidx,
                     float* __restrict__ out) {
    __shared__ int codes_s[64];
    __shared__ float wsum[4];
    const int nbase = blockIdx.x * 64;
    const int tid = threadIdx.x;
    if (tid < 64) {
        int n = nbase + tid;
        float bs = pscore[n];
        int bi = pidx[n];
#pragma unroll
        for (int p = 1; p < KS; ++p) {
            float s = pscore[p * 16384 + n];
            int ix = pidx[p * 16384 + n];
            if (s < bs || (s == bs && ix < bi)) { bs = s; bi = ix; }
        }
        codes_s[tid] = bi;
        out[4194305 + n] = (float)bi;
    }
    __syncthreads();
    const int lane = tid & 63;
    const int w = tid >> 6;
    const int n = nbase + lane;
    const int b = n >> 10, hw = n & 1023;
    const int code = codes_s[lane];
    const float* crow = cb + (size_t)code * 256;
    const float* zrow = z + (size_t)b * 262144 + hw;
    float* orow = out + (size_t)b * 262144 + hw;
    float part = 0.f;
    for (int j = 0; j < 64; ++j) {
        int d = w * 64 + j;
        float cv = crow[d];
        float ze = zrow[(size_t)d * 1024];
        orow[(size_t)d * 1024] = cv;
        float diff = ze - cv;
        part += diff * diff;
    }
#pragma unroll
    for (int off = 32; off > 0; off >>= 1) part += __shfl_down(part, off);
    if (lane == 0) wsum[w] = part;
    __syncthreads();
    if (tid == 0) {
        float t = (wsum[0] + wsum[1] + wsum[2] + wsum[3]) * (1.25f / 4194304.f);
        atomicAdd(out + 4194304, t);
    }
}

// ================= launcher =================
extern "C" void kernel_launch(void* const* d_in, const int* in_sizes, int n_in,
                              void* d_out, int out_size, void* d_ws, size_t ws_size,
                              hipStream_t stream) {
    const float* z = (const float*)d_in[0];
    const float* cb = (const float*)d_in[1];
    float* out = (float*)d_out;
    char* wsb = (char*)d_ws;

    if (ws_size >= WS_NEED) {
        float* zn = (float*)(wsb + ZN_B);
        unsigned* cnt = (unsigned*)(wsb + CNT_B);
        int* cand = (int*)(wsb + CAND_B);
        unsigned short* zh = (unsigned short*)(wsb + ZH_B);
        unsigned short* ch = (unsigned short*)(wsb + CH_B);

        hipMemsetAsync(wsb + CNT_B, 0, 65536, stream);
        hipMemsetAsync(out + 4194304, 0, sizeof(float), stream);

        prep_z_kernel<<<256, 256, 0, stream>>>(z, zn, zh);
        split_c_kernel<<<2048, 256, 0, stream>>>(cb, ch);
        gemm_screen32<<<256, 512, 0, stream>>>(zh, ch, cnt, cand);
        select_finalize<<<256, 256, 0, stream>>>(z, cb, zn, cnt, cand, out);
    } else {
        float* zn = (float*)wsb;
        float* pscore = (float*)wsb + PSCORE_OFF;
        int* pidx = (int*)((float*)wsb + PIDX_OFF);
        znorm_kernel<<<64, 256, 0, stream>>>(z, zn);
        dim3 grid(16384 / NT, KS);
        dist_argmin_kernel<<<grid, 256, 0, stream>>>(z, cb, zn, pscore, pidx);
        hipMemsetAsync(out + 4194304, 0, sizeof(float), stream);
        finalize_kernel<<<16384 / 64, 256, 0, stream>>>(z, cb, pscore, pidx, out);
    }
}